// Round 13
// baseline (411.724 us; speedup 1.0000x reference)
//
#include <hip/hip_runtime.h>

#define BB 64
#define LL 2048
#define TT 128
#define NROWS (BB * LL)
#define NBLK (NROWS / 8)      // 16384 blocks, 8 rows each, 256 per batch

// ws layout (4B units): den[0..63] num[64..127] bcnt[128..191](u32) gcnt[192](u32)
//                       brec[256..511] (64 batches x 4: lse0, lse0e, et0, pad)
//                       recs[512 .. 512+NBLK*8) (per-block partial records)
#define WS_NEED ((512 + NBLK * 8) * 4)

__device__ __forceinline__ void publish(float* p, float v) {
    __hip_atomic_store(p, v, __ATOMIC_RELAXED, __HIP_MEMORY_SCOPE_AGENT);
}
__device__ __forceinline__ float readback(const float* p) {
    return __hip_atomic_load(p, __ATOMIC_RELAXED, __HIP_MEMORY_SCOPE_AGENT);
}

typedef float v4f __attribute__((ext_vector_type(4)));
__device__ __forceinline__ float rl(float v, int k) {
    return __uint_as_float((unsigned)__builtin_amdgcn_readlane((int)__float_as_uint(v), k));
}

// half-wave (32-lane) reduce helpers
__device__ __forceinline__ float hmax(float x) {
    #pragma unroll
    for (int off = 16; off; off >>= 1) x = fmaxf(x, __shfl_xor(x, off));
    return x;
}
__device__ __forceinline__ float hsum(float x) {
    #pragma unroll
    for (int off = 16; off; off >>= 1) x += __shfl_xor(x, off);
    return x;
}

__global__ __launch_bounds__(256) void crf_fused_kernel(
    const float* __restrict__ em, const int* __restrict__ tgt,
    const int* __restrict__ mask, const float* __restrict__ start,
    const float* __restrict__ endt, const float* __restrict__ trans,
    float* __restrict__ den_out, float* __restrict__ num_out,
    unsigned* __restrict__ bcnt, unsigned* __restrict__ gcnt,
    float* __restrict__ brec, float* __restrict__ recs,
    float* __restrict__ out)
{
    const int t = threadIdx.x;
    const int w = t >> 6, l = t & 63;
    const int lh = l & 31, h = l >> 5;
    const int blk = blockIdx.x;
    const int b = blk >> 8;                 // batch
    const int bwb = blk & 255;              // block within batch
    const int li = bwb * 8 + w * 2 + h;     // local row in batch (0..2047)
    const size_t row = (size_t)b * LL + li; // global row

    __shared__ float rrow[8], r2row[8], erow[8];
    __shared__ int mrow[8];
    __shared__ int fin_sh;
    __shared__ unsigned og_sh;

    if (t < 8) mrow[t] = mask[(size_t)b * LL + bwb * 8 + t];

    // ---- per-row: r = lse(em), r2 = lse(em+end), etag = em[tgt] ----
    const float4 v = *(const float4*)(em + row * TT + lh * 4);
    const float4 ed = *(const float4*)(endt + lh * 4);

    float mx = hmax(fmaxf(fmaxf(v.x, v.y), fmaxf(v.z, v.w)));
    float sm = hsum(__expf(v.x - mx) + __expf(v.y - mx) + __expf(v.z - mx) + __expf(v.w - mx));
    const float rv = mx + __logf(sm);

    const float4 v2 = {v.x + ed.x, v.y + ed.y, v.z + ed.z, v.w + ed.w};
    float mx2 = hmax(fmaxf(fmaxf(v2.x, v2.y), fmaxf(v2.z, v2.w)));
    float sm2 = hsum(__expf(v2.x - mx2) + __expf(v2.y - mx2) + __expf(v2.z - mx2) + __expf(v2.w - mx2));
    const float r2v = mx2 + __logf(sm2);

    const int tg = tgt[row];                // uniform within half-wave
    const float c01 = (tg & 1) ? v.y : v.x;
    const float c23 = (tg & 1) ? v.w : v.z;
    const float cand = (tg & 2) ? c23 : c01;
    const float evv = __shfl(cand, (h << 5) + (tg >> 2));

    if (lh == 0) { rrow[w * 2 + h] = rv; r2row[w * 2 + h] = r2v; erow[w * 2 + h] = evv; }

    // ---- row-0-of-batch extras: lse0 = lse(start+em0), lse0e = lse(start+em0+end) ----
    float lse0 = 0.f, lse0e = 0.f;
    if (bwb == 0 && w == 0 && h == 0) {
        const float4 sv = *(const float4*)(start + lh * 4);
        const float4 a = {v.x + sv.x, v.y + sv.y, v.z + sv.z, v.w + sv.w};
        float ma = hmax(fmaxf(fmaxf(a.x, a.y), fmaxf(a.z, a.w)));
        float sa = hsum(__expf(a.x - ma) + __expf(a.y - ma) + __expf(a.z - ma) + __expf(a.w - ma));
        lse0 = ma + __logf(sa);
        const float4 a2 = {a.x + ed.x, a.y + ed.y, a.z + ed.z, a.w + ed.w};
        float ma2 = hmax(fmaxf(fmaxf(a2.x, a2.y), fmaxf(a2.z, a2.w)));
        float sa2 = hsum(__expf(a2.x - ma2) + __expf(a2.y - ma2) + __expf(a2.z - ma2) + __expf(a2.w - ma2));
        lse0e = ma2 + __logf(sa2);
    }
    __syncthreads();

    // ---- per-block aggregation + record publish + batch counter ----
    if (t == 0) {
        float rs = 0.f, es = 0.f, rl_ = 0.f, r2l = 0.f;
        int K = 0, last = -1;
        #pragma unroll
        for (int j = 0; j < 8; ++j) {
            const int lij = bwb * 8 + j;
            if (lij >= 1 && mrow[j] > 0) {
                ++K; rs += rrow[j]; es += erow[j];
                if (lij > last) { last = lij; rl_ = rrow[j]; r2l = r2row[j]; }
            }
        }
        float* rec = recs + (size_t)blk * 8;
        publish(&rec[0], rs);  publish(&rec[1], es);
        publish(&rec[2], rl_); publish(&rec[3], r2l);
        publish(&rec[4], (float)K); publish(&rec[5], (float)last);
        if (bwb == 0) {
            publish(&brec[b * 4 + 0], lse0);
            publish(&brec[b * 4 + 1], lse0e);
            publish(&brec[b * 4 + 2], erow[0]);
        }
        const unsigned old = __hip_atomic_fetch_add(&bcnt[b], 1u, __ATOMIC_ACQ_REL,
                                                    __HIP_MEMORY_SCOPE_AGENT);
        fin_sh = (old == 255u);   // counters memset to 0 each call -> true 256th block
    }
    __syncthreads();
    if (!fin_sh) return;

    // ================= FINISHER BLOCK for batch b =================
    const float* emb = em + (size_t)b * LL * TT;
    const int* mb = mask + (size_t)b * LL;

    // trans uniformity check (block-local, L2-hot)
    __shared__ int fsh[4];
    {
        const unsigned t0b = __float_as_uint(trans[0]);
        int ok = 1;
        for (int i = t; i < TT * TT; i += 256)
            ok &= (__float_as_uint(trans[i]) == t0b);
        const int wok = __all(ok);
        if (l == 0) fsh[w] = wok;
        __syncthreads();
    }
    const int uniform = fsh[0] & fsh[1] & fsh[2] & fsh[3];
    __syncthreads();

    if (uniform) {
        // ---- closed-form combine from 256 records ----
        const float* rec = recs + (size_t)((b << 8) + t) * 8;
        float rs = readback(&rec[0]), es = readback(&rec[1]);
        float rl_ = readback(&rec[2]), r2l = readback(&rec[3]);
        int K = (int)readback(&rec[4]);
        int last = (int)readback(&rec[5]);
        #pragma unroll
        for (int off = 32; off; off >>= 1) {
            rs += __shfl_xor(rs, off);
            es += __shfl_xor(es, off);
            K  += __shfl_xor(K, off);
            const int olast = __shfl_xor(last, off);
            const float orl = __shfl_xor(rl_, off);
            const float or2 = __shfl_xor(r2l, off);
            if (olast > last) { last = olast; rl_ = orl; r2l = or2; }
        }
        __shared__ float s_rs[4], s_es[4], s_rl[4], s_r2[4];
        __shared__ int s_K[4], s_last[4];
        if (l == 0) { s_rs[w] = rs; s_es[w] = es; s_rl[w] = rl_; s_r2[w] = r2l;
                      s_K[w] = K; s_last[w] = last; }
        __syncthreads();
        if (t == 0) {
            float g_rs = 0.f, g_es = 0.f, g_rl = 0.f, g_r2 = 0.f;
            int gK = 0, gl = -1;
            #pragma unroll
            for (int q = 0; q < 4; ++q) {
                g_rs += s_rs[q]; g_es += s_es[q]; gK += s_K[q];
                if (s_last[q] > gl) { gl = s_last[q]; g_rl = s_rl[q]; g_r2 = s_r2[q]; }
            }
            const float lse0 = readback(&brec[b * 4 + 0]);
            const float lse0e = readback(&brec[b * 4 + 1]);
            const float et0 = readback(&brec[b * 4 + 2]);
            const int tg0 = tgt[(size_t)b * LL];
            if (gK == 0) {
                publish(&den_out[b], lse0e);
                publish(&num_out[b], start[tg0] + et0 + endt[tg0]);
            } else {
                const float t0 = trans[0];
                publish(&den_out[b], lse0 + (float)gK * t0 + (g_rs - g_rl) + g_r2);
                const int tgl = tgt[(size_t)b * LL + gK];  // seq_ends = sum(mask)-1 = gK
                publish(&num_out[b], start[tg0] + et0 + (float)gK * t0 + g_es + endt[tgl]);
            }
        }
        __syncthreads();
    } else {
        // ---- general fallback: numerator + forward scan (round-6 validated core) ----
        {
            const int* tb = tgt + (size_t)b * LL;
            float acc = 0.f;
            int msum = 0;
            for (int x = t; x < LL; x += 256) {
                int mv = mb[x];
                msum += mv;
                if (x >= 1 && mv > 0) {
                    int tp = tb[x - 1], tc = tb[x];
                    acc += trans[tp * TT + tc] + emb[(size_t)x * TT + tc];
                }
            }
            __shared__ float sacc[4];
            __shared__ int smsum[4];
            #pragma unroll
            for (int off = 32; off; off >>= 1) {
                acc += __shfl_xor(acc, off);
                msum += __shfl_xor(msum, off);
            }
            if (l == 0) { sacc[w] = acc; smsum[w] = msum; }
            __syncthreads();
            if (t == 0) {
                float tot = sacc[0] + sacc[1] + sacc[2] + sacc[3];
                int total_mask = smsum[0] + smsum[1] + smsum[2] + smsum[3];
                int tg0 = tb[0];
                tot += start[tg0] + emb[tg0];
                int se = total_mask - 1;
                int lt = tb[se];
                tot += endt[lt];
                publish(&num_out[b], tot);
            }
            __syncthreads();
        }

        const int jr   = w & 1;
        const int tjr  = w >> 1;
        const int jown = (jr  << 6) + l;
        const int jtgt = (tjr << 6) + l;
        const int kbase = jr << 6;

        __shared__ float partial_sh[2][2][2][64];
        __shared__ float s0_sh[2];
        __shared__ int   mask_sh[LL];
        __shared__ float red[4], red2[4];

        for (int x = t; x < LL; x += 256) mask_sh[x] = mb[x];

        float cjE = -1e30f, cjS = -1e30f;
        for (int k = 0; k < TT; ++k) {
            cjE = fmaxf(cjE, trans[k * TT + jtgt]);
            cjS = fmaxf(cjS, trans[k * TT + jown]);
        }

#define EINIT(n) const v4f E##n = { \
    __expf(trans[(kbase + 4*(n) + 0) * TT + jtgt] - cjE), \
    __expf(trans[(kbase + 4*(n) + 1) * TT + jtgt] - cjE), \
    __expf(trans[(kbase + 4*(n) + 2) * TT + jtgt] - cjE), \
    __expf(trans[(kbase + 4*(n) + 3) * TT + jtgt] - cjE) };
        EINIT(0)  EINIT(1)  EINIT(2)  EINIT(3)
        EINIT(4)  EINIT(5)  EINIT(6)  EINIT(7)
        EINIT(8)  EINIT(9)  EINIT(10) EINIT(11)
        EINIT(12) EINIT(13) EINIT(14) EINIT(15)
#undef EINIT

        float s = start[jown] + emb[jown];
        if (t == 0) { s0_sh[0] = s; s0_sh[1] = s; }
        __syncthreads();
        float m_reg = s0_sh[0];

        float e0 = emb[(size_t)1 * TT + jown];
        float e1 = emb[(size_t)2 * TT + jown];
        float e2 = emb[(size_t)3 * TT + jown];
        float e3 = emb[(size_t)4 * TT + jown];
        float e4 = emb[(size_t)5 * TT + jown];
        float e5 = emb[(size_t)6 * TT + jown];
        float e6 = emb[(size_t)7 * TT + jown];
        float e7 = emb[(size_t)8 * TT + jown];

        for (int i = 1; i < LL; ++i) {
            const float em_cur = e0;
            e0 = e1; e1 = e2; e2 = e3; e3 = e4; e4 = e5; e5 = e6; e6 = e7;
            if (i + 8 < LL) e7 = emb[(size_t)(i + 8) * TT + jown];

            const float p = __expf(s - m_reg);

            float a0 = 0.f, a1 = 0.f, a2 = 0.f, a3 = 0.f;
#define FMA4(n) \
        a0 = fmaf(rl(p, 4*(n)+0), E##n.x, a0); \
        a1 = fmaf(rl(p, 4*(n)+1), E##n.y, a1); \
        a2 = fmaf(rl(p, 4*(n)+2), E##n.z, a2); \
        a3 = fmaf(rl(p, 4*(n)+3), E##n.w, a3);
            FMA4(0)  FMA4(1)  FMA4(2)  FMA4(3)
            FMA4(4)  FMA4(5)  FMA4(6)  FMA4(7)
            FMA4(8)  FMA4(9)  FMA4(10) FMA4(11)
            FMA4(12) FMA4(13) FMA4(14) FMA4(15)
#undef FMA4
            const float partial = (a0 + a2) + (a1 + a3);

            const int buf = i & 1;
            partial_sh[buf][tjr][jr][l] = partial;
            if (t == 0) s0_sh[buf] = s;

            asm volatile("s_waitcnt lgkmcnt(0)" ::: "memory");
            __builtin_amdgcn_s_barrier();
            asm volatile("" ::: "memory");

            const float pa = partial_sh[buf][jr][0][l];
            const float pb = partial_sh[buf][jr][1][l];
            const float mnext = s0_sh[buf];
            const float acc2 = pa + pb;

            const float snew = em_cur + m_reg + cjS + __logf(acc2);
            s = (mask_sh[i] > 0) ? snew : s;
            m_reg = mnext;
        }

        float vv = s + endt[jown];
        float m2 = vv;
        #pragma unroll
        for (int off = 32; off; off >>= 1) m2 = fmaxf(m2, __shfl_xor(m2, off));
        if (l == 0) red2[w] = m2;
        __syncthreads();
        m2 = fmaxf(fmaxf(red2[0], red2[1]), fmaxf(red2[2], red2[3]));
        float e = (w < 2) ? __expf(vv - m2) : 0.f;
        #pragma unroll
        for (int off = 32; off; off >>= 1) e += __shfl_xor(e, off);
        if (l == 0) red[w] = e;
        __syncthreads();
        if (t == 0) publish(&den_out[b], m2 + __logf(red[0] + red[1] + red[2] + red[3]));
        __syncthreads();
    }

    // ---- global last-batch-done: out = sum_b (den_b - num_b) ----
    if (t == 0)
        og_sh = __hip_atomic_fetch_add(gcnt, 1u, __ATOMIC_ACQ_REL,
                                       __HIP_MEMORY_SCOPE_AGENT);
    __syncthreads();
    if (og_sh == BB - 1 && t < 64) {     // true 64th finisher (gcnt memset to 0)
        float v = readback(&den_out[t]) - readback(&num_out[t]);
        #pragma unroll
        for (int off = 32; off; off >>= 1) v += __shfl_xor(v, off);
        if (t == 0) out[0] = v;
    }
}

// ---------------- fallback (small ws): per-batch general + final ----------------
__global__ __launch_bounds__(256, 1) void crf_general_kernel(
    const float* __restrict__ em, const int* __restrict__ tgt,
    const int* __restrict__ mask, const float* __restrict__ start,
    const float* __restrict__ endt, const float* __restrict__ trans,
    float* __restrict__ den_out, float* __restrict__ num_out)
{
    const int b = blockIdx.x;
    const int t = threadIdx.x;
    const int w = t >> 6, l = t & 63;
    const float* emb = em + (size_t)b * LL * TT;
    const int* mb = mask + (size_t)b * LL;
    {
        const int* tb = tgt + (size_t)b * LL;
        float acc = 0.f;
        int msum = 0;
        for (int x = t; x < LL; x += 256) {
            int mv = mb[x];
            msum += mv;
            if (x >= 1 && mv > 0) {
                int tp = tb[x - 1], tc = tb[x];
                acc += trans[tp * TT + tc] + emb[(size_t)x * TT + tc];
            }
        }
        __shared__ float sacc[4];
        __shared__ int smsum[4];
        #pragma unroll
        for (int off = 32; off; off >>= 1) {
            acc += __shfl_xor(acc, off);
            msum += __shfl_xor(msum, off);
        }
        if (l == 0) { sacc[w] = acc; smsum[w] = msum; }
        __syncthreads();
        if (t == 0) {
            float tot = sacc[0] + sacc[1] + sacc[2] + sacc[3];
            int total_mask = smsum[0] + smsum[1] + smsum[2] + smsum[3];
            int tg0 = tb[0];
            tot += start[tg0] + emb[tg0];
            num_out[b] = tot + endt[tb[total_mask - 1]];
        }
        __syncthreads();
    }

    const int jr = w & 1, tjr = w >> 1;
    const int jown = (jr << 6) + l, jtgt = (tjr << 6) + l;
    const int kbase = jr << 6;
    __shared__ float partial_sh[2][2][2][64];
    __shared__ float s0_sh[2];
    __shared__ int mask_sh[LL];
    __shared__ float red[4], red2[4];
    for (int x = t; x < LL; x += 256) mask_sh[x] = mb[x];
    float cjE = -1e30f, cjS = -1e30f;
    for (int k = 0; k < TT; ++k) {
        cjE = fmaxf(cjE, trans[k * TT + jtgt]);
        cjS = fmaxf(cjS, trans[k * TT + jown]);
    }
#define EINIT(n) const v4f E##n = { \
    __expf(trans[(kbase + 4*(n) + 0) * TT + jtgt] - cjE), \
    __expf(trans[(kbase + 4*(n) + 1) * TT + jtgt] - cjE), \
    __expf(trans[(kbase + 4*(n) + 2) * TT + jtgt] - cjE), \
    __expf(trans[(kbase + 4*(n) + 3) * TT + jtgt] - cjE) };
    EINIT(0)  EINIT(1)  EINIT(2)  EINIT(3)
    EINIT(4)  EINIT(5)  EINIT(6)  EINIT(7)
    EINIT(8)  EINIT(9)  EINIT(10) EINIT(11)
    EINIT(12) EINIT(13) EINIT(14) EINIT(15)
#undef EINIT
    float s = start[jown] + emb[jown];
    if (t == 0) { s0_sh[0] = s; s0_sh[1] = s; }
    __syncthreads();
    float m_reg = s0_sh[0];
    float e0 = emb[(size_t)1 * TT + jown], e1 = emb[(size_t)2 * TT + jown];
    float e2 = emb[(size_t)3 * TT + jown], e3 = emb[(size_t)4 * TT + jown];
    float e4 = emb[(size_t)5 * TT + jown], e5 = emb[(size_t)6 * TT + jown];
    float e6 = emb[(size_t)7 * TT + jown], e7 = emb[(size_t)8 * TT + jown];
    for (int i = 1; i < LL; ++i) {
        const float em_cur = e0;
        e0 = e1; e1 = e2; e2 = e3; e3 = e4; e4 = e5; e5 = e6; e6 = e7;
        if (i + 8 < LL) e7 = emb[(size_t)(i + 8) * TT + jown];
        const float p = __expf(s - m_reg);
        float a0 = 0.f, a1 = 0.f, a2 = 0.f, a3 = 0.f;
#define FMA4(n) \
        a0 = fmaf(rl(p, 4*(n)+0), E##n.x, a0); \
        a1 = fmaf(rl(p, 4*(n)+1), E##n.y, a1); \
        a2 = fmaf(rl(p, 4*(n)+2), E##n.z, a2); \
        a3 = fmaf(rl(p, 4*(n)+3), E##n.w, a3);
        FMA4(0)  FMA4(1)  FMA4(2)  FMA4(3)
        FMA4(4)  FMA4(5)  FMA4(6)  FMA4(7)
        FMA4(8)  FMA4(9)  FMA4(10) FMA4(11)
        FMA4(12) FMA4(13) FMA4(14) FMA4(15)
#undef FMA4
        const float partial = (a0 + a2) + (a1 + a3);
        const int buf = i & 1;
        partial_sh[buf][tjr][jr][l] = partial;
        if (t == 0) s0_sh[buf] = s;
        asm volatile("s_waitcnt lgkmcnt(0)" ::: "memory");
        __builtin_amdgcn_s_barrier();
        asm volatile("" ::: "memory");
        const float pa = partial_sh[buf][jr][0][l];
        const float pb = partial_sh[buf][jr][1][l];
        const float mnext = s0_sh[buf];
        const float snew = em_cur + m_reg + cjS + __logf(pa + pb);
        s = (mask_sh[i] > 0) ? snew : s;
        m_reg = mnext;
    }
    float vv = s + endt[jown];
    float m2 = vv;
    #pragma unroll
    for (int off = 32; off; off >>= 1) m2 = fmaxf(m2, __shfl_xor(m2, off));
    if (l == 0) red2[w] = m2;
    __syncthreads();
    m2 = fmaxf(fmaxf(red2[0], red2[1]), fmaxf(red2[2], red2[3]));
    float e = (w < 2) ? __expf(vv - m2) : 0.f;
    #pragma unroll
    for (int off = 32; off; off >>= 1) e += __shfl_xor(e, off);
    if (l == 0) red[w] = e;
    __syncthreads();
    if (t == 0) den_out[b] = m2 + __logf(red[0] + red[1] + red[2] + red[3]);
}

__global__ void crf_final_kernel(const float* __restrict__ den,
                                 const float* __restrict__ num,
                                 float* __restrict__ out)
{
    int t = threadIdx.x;
    float v = den[t] - num[t];
    #pragma unroll
    for (int off = 32; off; off >>= 1) v += __shfl_xor(v, off);
    if (t == 0) out[0] = v;
}

extern "C" void kernel_launch(void* const* d_in, const int* in_sizes, int n_in,
                              void* d_out, int out_size, void* d_ws, size_t ws_size,
                              hipStream_t stream)
{
    const float* em    = (const float*)d_in[0];   // [B,L,T] f32
    const int*   tgt   = (const int*)d_in[1];     // [B,L]
    const int*   mask  = (const int*)d_in[2];     // [B,L]
    const float* start = (const float*)d_in[3];   // [T]
    const float* endt  = (const float*)d_in[4];   // [T]
    const float* trans = (const float*)d_in[5];   // [T,T]
    float* out = (float*)d_out;

    float*    den  = (float*)d_ws;             // [64]
    float*    num  = den + BB;                 // [64]
    unsigned* bcnt = (unsigned*)(den + 128);   // [64]
    unsigned* gcnt = (unsigned*)(den + 192);   // [1]
    float*    brec = den + 256;                // [64*4]
    float*    recs = den + 512;                // [NBLK*8]

    if (ws_size >= (size_t)WS_NEED) {
        // zero bcnt[64] + gcnt (65 contiguous u32) every call: finisher election
        // requires counters to start at 0 (graph-capture-legal memset node).
        hipMemsetAsync((void*)bcnt, 0, 65 * sizeof(unsigned), stream);
        crf_fused_kernel<<<NBLK, 256, 0, stream>>>(em, tgt, mask, start, endt, trans,
                                                   den, num, bcnt, gcnt, brec, recs, out);
    } else {
        crf_general_kernel<<<BB, 256, 0, stream>>>(em, tgt, mask, start, endt, trans,
                                                   den, num);
        crf_final_kernel<<<1, 64, 0, stream>>>(den, num, out);
    }
}

// Round 14
// 28.100 us; speedup vs baseline: 14.6523x; 14.6523x over previous
//
#include <hip/hip_runtime.h>

#define BB 64
#define LL 2048
#define TT 128
#define NROWS (BB * LL)

// ws layout (4B units): den[0..63] num[64..127] okpart[128..191] (u32)
//                       r[256 .. 256+NROWS) etag[256+NROWS .. 256+2*NROWS)
#define WS_NEED ((256 + 2 * NROWS) * 4)

// ---------------- fused: per-row lse + gold-tag gather + trans uniformity check ----
// 256 thr = 4 waves; wave = 2 rows (float4/lane). Blocks 0..63 also check a
// 256-entry slice of trans and write okpart[block].
__global__ __launch_bounds__(256) void crf_rowlse_kernel(
    const float* __restrict__ em, const int* __restrict__ tgt,
    const float* __restrict__ trans,
    float* __restrict__ r, float* __restrict__ etag,
    unsigned* __restrict__ okpart)
{
    const int t = threadIdx.x;
    const int wave = t >> 6, l = t & 63;
    const int h = l >> 5;                       // half-wave
    const int wv = blockIdx.x * 4 + wave;       // global wave id
    const int row = wv * 2 + h;                 // row handled by this half

    __shared__ int oksh[4];
    if (blockIdx.x < 64) {
        const unsigned t0b = __float_as_uint(trans[0]);
        const int ok = (__float_as_uint(trans[blockIdx.x * 256 + t]) == t0b);
        const int wok = __all(ok);
        if (l == 0) oksh[wave] = wok;
        __syncthreads();
        if (t == 0) okpart[blockIdx.x] = (unsigned)(oksh[0] & oksh[1] & oksh[2] & oksh[3]);
    }

    // row lse (float4: lanes 0-31 row, lanes 32-63 row+1)
    const float4 v = *(const float4*)(em + (size_t)wv * 256 + l * 4);
    float mx = fmaxf(fmaxf(v.x, v.y), fmaxf(v.z, v.w));
    #pragma unroll
    for (int off = 16; off; off >>= 1) mx = fmaxf(mx, __shfl_xor(mx, off));
    float s = __expf(v.x - mx) + __expf(v.y - mx) + __expf(v.z - mx) + __expf(v.w - mx);
    #pragma unroll
    for (int off = 16; off; off >>= 1) s += __shfl_xor(s, off);

    // gold-tag gather: etag[row] = em[row][tg]
    const int tg = tgt[row];                    // uniform within half-wave
    const float c01 = (tg & 1) ? v.y : v.x;
    const float c23 = (tg & 1) ? v.w : v.z;
    const float cand = (tg & 2) ? c23 : c01;
    const float ev = __shfl(cand, (h << 5) + (tg >> 2));

    if ((l & 31) == 0) {
        r[row] = mx + __logf(s);
        etag[row] = ev;
    }
}

// ---------------- per-batch: uniform-path combine OR general num+forward ---------
typedef float v4f __attribute__((ext_vector_type(4)));
__device__ __forceinline__ float rl(float v, int k) {
    return __uint_as_float((unsigned)__builtin_amdgcn_readlane((int)__float_as_uint(v), k));
}

__global__ __launch_bounds__(256, 1) __attribute__((amdgpu_waves_per_eu(1, 2)))
void crf_perbatch_kernel(
    const float* __restrict__ em, const int* __restrict__ tgt,
    const int* __restrict__ mask, const float* __restrict__ start,
    const float* __restrict__ endt, const float* __restrict__ trans,
    const unsigned* __restrict__ okpart, const float* __restrict__ r,
    const float* __restrict__ etag,
    float* __restrict__ den_out, float* __restrict__ num_out)
{
    const int b = blockIdx.x;
    const int t = threadIdx.x;
    const int w = t >> 6, l = t & 63;

    __shared__ int fsh[4];
    int uniform = 0;
    if (okpart) {
        const int myok = (t < 64) ? (int)okpart[t] : 1;
        const int wok = __all(myok);
        if (l == 0) fsh[w] = wok;
        __syncthreads();
        uniform = fsh[0] & fsh[1] & fsh[2] & fsh[3];
        __syncthreads();
    }

    const float* emb = em + (size_t)b * LL * TT;
    const int* mb = mask + (size_t)b * LL;

    if (uniform) {
        // ------- combine path: den_b and num_b in closed form -------
        const float* rb = r + (size_t)b * LL;
        const float* eb = etag + (size_t)b * LL;

        __shared__ float s_rs[4], s_es[4];
        __shared__ int s_k[4], s_last[4];
        __shared__ int g_k, g_last;
        __shared__ float g_rs, g_es;
        __shared__ float s_max[4], s_sum[4];

        int k = 0, last = 0;
        float rs = 0.f, es = 0.f;
        for (int i = t; i < LL; i += 256) {
            const int mv = (i >= 1) ? mb[i] : 0;
            if (mv > 0) { ++k; last = (i > last) ? i : last; rs += rb[i]; es += eb[i]; }
        }
        #pragma unroll
        for (int off = 32; off; off >>= 1) {
            k += __shfl_xor(k, off);
            last = max(last, __shfl_xor(last, off));
            rs += __shfl_xor(rs, off);
            es += __shfl_xor(es, off);
        }
        if (l == 0) { s_k[w] = k; s_last[w] = last; s_rs[w] = rs; s_es[w] = es; }
        __syncthreads();
        if (t == 0) {
            g_k = s_k[0] + s_k[1] + s_k[2] + s_k[3];
            g_last = max(max(s_last[0], s_last[1]), max(s_last[2], s_last[3]));
            g_rs = s_rs[0] + s_rs[1] + s_rs[2] + s_rs[3];
            g_es = s_es[0] + s_es[1] + s_es[2] + s_es[3];
        }
        __syncthreads();
        const int K = g_k;
        const int lastI = g_last;

        // waves 0,1: lse(start+em0 [+end if K==0]); waves 2,3: lse(em_last+end)
        float x;
        if (t < 128) {
            x = start[t] + emb[t] + ((K == 0) ? endt[t] : 0.f);
        } else {
            const int j = t - 128;
            x = (K > 0) ? (emb[(size_t)lastI * TT + j] + endt[j]) : -1e30f;
        }
        float mx = x;
        #pragma unroll
        for (int off = 32; off; off >>= 1) mx = fmaxf(mx, __shfl_xor(mx, off));
        if (l == 0) s_max[w] = mx;
        __syncthreads();
        const float m01 = fmaxf(s_max[0], s_max[1]);
        const float m23 = fmaxf(s_max[2], s_max[3]);
        float e = __expf(x - ((t < 128) ? m01 : m23));
        #pragma unroll
        for (int off = 32; off; off >>= 1) e += __shfl_xor(e, off);
        if (l == 0) s_sum[w] = e;
        __syncthreads();
        if (t == 0) {
            const float t0 = trans[0];
            const int tg0 = tgt[(size_t)b * LL];
            const float et0 = eb[0];
            const float lse0 = m01 + __logf(s_sum[0] + s_sum[1]);
            if (K == 0) {
                den_out[b] = lse0;
                num_out[b] = start[tg0] + et0 + endt[tg0];
            } else {
                const float lseE = m23 + __logf(s_sum[2] + s_sum[3]);
                den_out[b] = lse0 + (float)K * t0 + (g_rs - rb[lastI]) + lseE;
                const int tgl = tgt[(size_t)b * LL + K];   // seq_ends = sum(mask)-1 = K
                num_out[b] = start[tg0] + et0 + (float)K * t0 + g_es + endt[tgl];
            }
        }
        return;
    }

    // ------- general path: numerator, then forward scan (round-6 validated) -------
    {
        const int* tb = tgt + (size_t)b * LL;
        float acc = 0.f;
        int msum = 0;
        for (int x = t; x < LL; x += 256) {
            int mv = mb[x];
            msum += mv;
            if (x >= 1 && mv > 0) {
                int tp = tb[x - 1], tc = tb[x];
                acc += trans[tp * TT + tc] + emb[(size_t)x * TT + tc];
            }
        }
        __shared__ float sacc[4];
        __shared__ int smsum[4];
        #pragma unroll
        for (int off = 32; off; off >>= 1) {
            acc += __shfl_xor(acc, off);
            msum += __shfl_xor(msum, off);
        }
        if (l == 0) { sacc[w] = acc; smsum[w] = msum; }
        __syncthreads();
        if (t == 0) {
            float tot = sacc[0] + sacc[1] + sacc[2] + sacc[3];
            int total_mask = smsum[0] + smsum[1] + smsum[2] + smsum[3];
            int t0 = tb[0];
            tot += start[t0] + emb[t0];
            int se = total_mask - 1;
            int lt = tb[se];
            tot += endt[lt];
            num_out[b] = tot;
        }
        __syncthreads();
    }

    const int jr   = w & 1;
    const int tjr  = w >> 1;
    const int jown = (jr  << 6) + l;
    const int jtgt = (tjr << 6) + l;
    const int kbase = jr << 6;

    __shared__ float partial_sh[2][2][2][64];
    __shared__ float s0_sh[2];
    __shared__ int   mask_sh[LL];
    __shared__ float red[4], red2[4];

    for (int x = t; x < LL; x += 256) mask_sh[x] = mb[x];

    float cjE = -1e30f, cjS = -1e30f;
    for (int k = 0; k < TT; ++k) {
        cjE = fmaxf(cjE, trans[k * TT + jtgt]);
        cjS = fmaxf(cjS, trans[k * TT + jown]);
    }

#define EINIT(n) const v4f E##n = { \
    __expf(trans[(kbase + 4*(n) + 0) * TT + jtgt] - cjE), \
    __expf(trans[(kbase + 4*(n) + 1) * TT + jtgt] - cjE), \
    __expf(trans[(kbase + 4*(n) + 2) * TT + jtgt] - cjE), \
    __expf(trans[(kbase + 4*(n) + 3) * TT + jtgt] - cjE) };
    EINIT(0)  EINIT(1)  EINIT(2)  EINIT(3)
    EINIT(4)  EINIT(5)  EINIT(6)  EINIT(7)
    EINIT(8)  EINIT(9)  EINIT(10) EINIT(11)
    EINIT(12) EINIT(13) EINIT(14) EINIT(15)
#undef EINIT

    float s = start[jown] + emb[jown];
    if (t == 0) { s0_sh[0] = s; s0_sh[1] = s; }
    __syncthreads();
    float m_reg = s0_sh[0];

    float e0 = emb[(size_t)1 * TT + jown];
    float e1 = emb[(size_t)2 * TT + jown];
    float e2 = emb[(size_t)3 * TT + jown];
    float e3 = emb[(size_t)4 * TT + jown];
    float e4 = emb[(size_t)5 * TT + jown];
    float e5 = emb[(size_t)6 * TT + jown];
    float e6 = emb[(size_t)7 * TT + jown];
    float e7 = emb[(size_t)8 * TT + jown];

    for (int i = 1; i < LL; ++i) {
        const float em_cur = e0;
        e0 = e1; e1 = e2; e2 = e3; e3 = e4; e4 = e5; e5 = e6; e6 = e7;
        if (i + 8 < LL) e7 = emb[(size_t)(i + 8) * TT + jown];

        const float p = __expf(s - m_reg);

        float a0 = 0.f, a1 = 0.f, a2 = 0.f, a3 = 0.f;
#define FMA4(n) \
        a0 = fmaf(rl(p, 4*(n)+0), E##n.x, a0); \
        a1 = fmaf(rl(p, 4*(n)+1), E##n.y, a1); \
        a2 = fmaf(rl(p, 4*(n)+2), E##n.z, a2); \
        a3 = fmaf(rl(p, 4*(n)+3), E##n.w, a3);
        FMA4(0)  FMA4(1)  FMA4(2)  FMA4(3)
        FMA4(4)  FMA4(5)  FMA4(6)  FMA4(7)
        FMA4(8)  FMA4(9)  FMA4(10) FMA4(11)
        FMA4(12) FMA4(13) FMA4(14) FMA4(15)
#undef FMA4
        const float partial = (a0 + a2) + (a1 + a3);

        const int buf = i & 1;
        partial_sh[buf][tjr][jr][l] = partial;
        if (t == 0) s0_sh[buf] = s;

        asm volatile("s_waitcnt lgkmcnt(0)" ::: "memory");
        __builtin_amdgcn_s_barrier();
        asm volatile("" ::: "memory");

        const float pa = partial_sh[buf][jr][0][l];
        const float pb = partial_sh[buf][jr][1][l];
        const float mnext = s0_sh[buf];
        const float acc2 = pa + pb;

        const float snew = em_cur + m_reg + cjS + __logf(acc2);
        s = (mask_sh[i] > 0) ? snew : s;
        m_reg = mnext;
    }

    float v = s + endt[jown];
    float m2 = v;
    #pragma unroll
    for (int off = 32; off; off >>= 1) m2 = fmaxf(m2, __shfl_xor(m2, off));
    if (l == 0) red2[w] = m2;
    __syncthreads();
    m2 = fmaxf(fmaxf(red2[0], red2[1]), fmaxf(red2[2], red2[3]));
    float e = (w < 2) ? __expf(v - m2) : 0.f;
    #pragma unroll
    for (int off = 32; off; off >>= 1) e += __shfl_xor(e, off);
    if (l == 0) red[w] = e;
    __syncthreads();
    if (t == 0) den_out[b] = m2 + __logf(red[0] + red[1] + red[2] + red[3]);
}

// ---------------- final: out = sum_b (den_b - num_b) ----------------
__global__ void crf_final_kernel(const float* __restrict__ den,
                                 const float* __restrict__ num,
                                 float* __restrict__ out)
{
    int t = threadIdx.x;   // 64 threads == BB
    float v = den[t] - num[t];
    #pragma unroll
    for (int off = 32; off; off >>= 1) v += __shfl_xor(v, off);
    if (t == 0) out[0] = v;
}

extern "C" void kernel_launch(void* const* d_in, const int* in_sizes, int n_in,
                              void* d_out, int out_size, void* d_ws, size_t ws_size,
                              hipStream_t stream)
{
    const float* em    = (const float*)d_in[0];   // [B,L,T] f32
    const int*   tgt   = (const int*)d_in[1];     // [B,L]
    const int*   mask  = (const int*)d_in[2];     // [B,L]
    const float* start = (const float*)d_in[3];   // [T]
    const float* endt  = (const float*)d_in[4];   // [T]
    const float* trans = (const float*)d_in[5];   // [T,T]
    float* out = (float*)d_out;

    float*    den    = (float*)d_ws;             // [64]
    float*    num    = den + BB;                 // [64]
    unsigned* okpart = (unsigned*)(den + 128);   // [64]
    float*    r      = den + 256;                // [NROWS]
    float*    etag   = r + NROWS;                // [NROWS]

    if (ws_size >= (size_t)WS_NEED) {
        crf_rowlse_kernel<<<NROWS / 8, 256, 0, stream>>>(em, tgt, trans, r, etag, okpart);
        crf_perbatch_kernel<<<BB, 256, 0, stream>>>(em, tgt, mask, start, endt, trans,
                                                    okpart, r, etag, den, num);
        crf_final_kernel<<<1, 64, 0, stream>>>(den, num, out);
    } else {
        crf_perbatch_kernel<<<BB, 256, 0, stream>>>(em, tgt, mask, start, endt, trans,
                                                    nullptr, nullptr, nullptr, den, num);
        crf_final_kernel<<<1, 64, 0, stream>>>(den, num, out);
    }
}